// Round 9
// baseline (83.945 us; speedup 1.0000x reference)
//
#include <hip/hip_runtime.h>

#define N 512
#define ADJW (N/64)
#define MAXC 64
typedef unsigned long long ull;

#define ADJ_OFF    0
#define ROWCNT_OFF 32768
#define PAIRS_OFF  34816

__device__ __forceinline__ float limit_period_f(float v){
    const float TWO_PI_F = 6.2831853071795864769f;
    return v - floorf(v/TWO_PI_F + 0.5f)*TWO_PI_F;
}

// Kernel A: cheap conservative test on all pairs, zero adj rows, write
// per-row candidate list at deterministic slots (no atomics, no init kernel).
__global__ __launch_bounds__(512) void pair_kernel(const float* __restrict__ boxes,
                                                   ull* __restrict__ adj,
                                                   int* __restrict__ rowcnt,
                                                   int* __restrict__ pairs){
    int i = blockIdx.x;
    int t = threadIdx.x;
    int lane = t & 63, w = t >> 6;
    __shared__ int s_wcnt[8];
    if(t < ADJW) adj[i*ADJW + t] = 0ull;

    float bi0=boxes[i*7+0], bi1=boxes[i*7+1], bi2=boxes[i*7+2], bi3=boxes[i*7+3],
          bi4=boxes[i*7+4], bi5=boxes[i*7+5];
    int j = t;
    float bj0=boxes[j*7+0], bj1=boxes[j*7+1], bj2=boxes[j*7+2], bj3=boxes[j*7+3],
          bj4=boxes[j*7+4], bj5=boxes[j*7+5];
    float topi = bi2 + bi3*0.5f, boti = bi2 - bi3*0.5f;
    float topj = bj2 + bj3*0.5f, botj = bj2 - bj3*0.5f;
    float oh = fminf(topi, topj) - fmaxf(boti, botj);
    float dx = bi0 - bj0, dy = bi1 - bj1;
    float ra = 0.5f*sqrtf(bi5*bi5 + bi4*bi4);
    float rb = 0.5f*sqrtf(bj5*bj5 + bj4*bj4);
    float rr = ra + rb + 0.01f;
    bool cand = (dx*dx + dy*dy <= rr*rr) && (oh > 0.0f);

    ull m = __ballot(cand);
    if(lane == 0) s_wcnt[w] = __popcll(m);
    int prefix = __popcll(m & ((1ull<<lane) - 1ull));
    __syncthreads();
    int base = 0, C = 0;
    #pragma unroll
    for(int k=0;k<8;++k){ int c = s_wcnt[k]; if(k < w) base += c; C += c; }
    if(cand){
        int pos = base + prefix;
        if(pos < MAXC) pairs[i*MAXC + pos] = j;
    }
    if(t == 0) rowcnt[i] = (C < MAXC) ? C : MAXC;
}

// Kernel B: lane-parallel polygon clip, globally LOAD-BALANCED. Wave g
// (g = blockIdx*8 + wv, 4096 waves) grid-strides the flat slot space
// [0, 512*64): slots g, g+4096, ... A skewed row's candidates spread across
// many waves -> worst-case per-wave chain count drops from ~8 to ~1-2.
// All per-slot float ops identical to the r7/r8 passing code.
__global__ __launch_bounds__(512) void geom_kernel(const float* __restrict__ boxes,
                                                   const int* __restrict__ pairs,
                                                   const int* __restrict__ rowcnt,
                                                   ull* __restrict__ adj){
    int t = threadIdx.x;
    int l  = t & 63;
    int wv = t >> 6;
    int g = blockIdx.x*8 + wv;          // 0..4095
    __shared__ float s_px[8][24], s_py[8][24];
    __shared__ float s_rx[8][24], s_ry[8][24], s_tm[8][24];
    const float tx[4] = {0.5f, 0.5f, -0.5f, -0.5f};
    const float ty[4] = {0.5f, -0.5f, -0.5f, 0.5f};

    for(int s = g; s < N*MAXC; s += 4096){
        int i = s >> 6, k = s & 63;     // wave-uniform
        if(k >= rowcnt[i]) continue;    // uniform branch: whole wave skips
        int jj = pairs[s];

        float bi0=boxes[i*7+0], bi1=boxes[i*7+1], bi2=boxes[i*7+2], bi3=boxes[i*7+3],
              bi4=boxes[i*7+4], bi5=boxes[i*7+5], bi6=boxes[i*7+6];
        float cj0=boxes[jj*7+0], cj1=boxes[jj*7+1], cj2=boxes[jj*7+2], cj3=boxes[jj*7+3],
              cj4=boxes[jj*7+4], cj5=boxes[jj*7+5], cj6=boxes[jj*7+6];
        float voli = bi3*bi4*bi5;
        float volj = cj3*cj4*cj5;
        float topi = bi2 + bi3*0.5f, boti = bi2 - bi3*0.5f;
        float topj = cj2 + cj3*0.5f, botj = cj2 - cj3*0.5f;
        float oh = fminf(topi, topj) - fmaxf(boti, botj);  // > 0 for candidates

        float yawi = limit_period_f(bi6);
        float yawj = limit_period_f(cj6);
        float cA = cosf(yawi), sA = sinf(yawi);
        float cB = cosf(yawj), sB = sinf(yawj);
        float axv[4], ayv[4], bxv[4], byv[4];
        #pragma unroll
        for(int kk=0;kk<4;++kk){
            float px = tx[kk]*bi5, py = ty[kk]*bi4;
            axv[kk] = px*cA - py*sA + bi0;
            ayv[kk] = px*sA + py*cA + bi1;
            float qx = tx[kk]*cj5, qy = ty[kk]*cj4;
            bxv[kk] = qx*cB - qy*sB + cj0;
            byv[kk] = qx*sB + qy*cB + cj1;
        }

        // ---- per-slot candidate on lane l ----
        const float EPSQ = 1e-5f;
        bool valid = false;
        float px = 0.f, py = 0.f;
        if(l < 16){
            int e1 = l >> 2, e2 = l & 3;
            float a1x=axv[e1], a1y=ayv[e1];
            float d1x=axv[(e1+1)&3]-a1x, d1y=ayv[(e1+1)&3]-a1y;
            float b1x=bxv[e2], b1y=byv[e2];
            float d2x=bxv[(e2+1)&3]-b1x, d2y=byv[(e2+1)&3]-b1y;
            float den = d1x*d2y - d1y*d2x;
            bool okd = fabsf(den) > 1e-8f;
            float dens = okd ? den : 1e-8f;
            float wx = b1x-a1x, wy = b1y-a1y;
            float tt = (wx*d2y - wy*d2x)/dens;
            float uu = (wx*d1y - wy*d1x)/dens;
            valid = okd && (tt>=0.f) && (tt<=1.f) && (uu>=0.f) && (uu<=1.f);
            px = a1x + tt*d1x;
            py = a1y + tt*d1y;
        } else if(l < 20){
            int kk = l - 16;
            px = axv[kk]; py = ayv[kk];
            bool le=true, ge=true;
            #pragma unroll
            for(int e=0;e<4;++e){
                float qx=bxv[e], qy=byv[e];
                float ux=bxv[(e+1)&3]-qx, uy=byv[(e+1)&3]-qy;
                float cc = ux*(py-qy) - uy*(px-qx);
                le = le && (cc <= EPSQ);
                ge = ge && (cc >= -EPSQ);
            }
            valid = le || ge;
        } else if(l < 24){
            int kk = l - 20;
            px = bxv[kk]; py = byv[kk];
            bool le=true, ge=true;
            #pragma unroll
            for(int e=0;e<4;++e){
                float qx=axv[e], qy=ayv[e];
                float ux=axv[(e+1)&3]-qx, uy=ayv[(e+1)&3]-qy;
                float cc = ux*(py-qy) - uy*(px-qx);
                le = le && (cc <= EPSQ);
                ge = ge && (cc >= -EPSQ);
            }
            valid = le || ge;
        }

        ull bm = __ballot(valid);
        int c = __popcll(bm);
        float cntf = (float)c;

        // ---- centroid: lane 0 sums 24 slot values in slot order (invalid -> 0.0) ----
        if(l < 24){
            s_px[wv][l] = valid ? px : 0.f;
            s_py[wv][l] = valid ? py : 0.f;
        }
        asm volatile("s_waitcnt lgkmcnt(0)" ::: "memory");
        float sx = 0.f, sy = 0.f;
        if(l == 0){
            #pragma unroll
            for(int kk=0;kk<24;++kk){ sx += s_px[wv][kk]; sy += s_py[wv][kk]; }
        }
        sx = __shfl(sx, 0);
        sy = __shfl(sy, 0);
        float denomc = fmaxf(cntf, 1.f);
        float cenx = sx/denomc, ceny = sy/denomc;

        // ---- rel + parallel atan2 ----
        float relx = valid ? (px - cenx) : 0.f;
        float rely = valid ? (py - ceny) : 0.f;
        float ang  = valid ? atan2f(rely, relx) : 1e9f;

        // ---- stable parallel rank over 24 slots ----
        int r = 0;
        if(l < 24){
            for(int qq=0; qq<24; ++qq){
                float aq = __shfl(ang, qq);
                if(aq < ang) r++;
                else if(aq == ang && qq < l) r++;
            }
        }

        // ---- scatter rel by rank; cross-term per sorted position ----
        if(l < 24){
            s_rx[wv][r] = relx;
            s_ry[wv][r] = rely;
        }
        asm volatile("s_waitcnt lgkmcnt(0)" ::: "memory");
        if(l < 24){
            int nxt = (r+1 < c) ? (r+1) : 0;
            float nx = s_rx[wv][nxt], ny = s_ry[wv][nxt];
            float tm = (r < c) ? (relx*ny - rely*nx) : 0.f;
            s_tm[wv][r] = tm;
        }
        asm volatile("s_waitcnt lgkmcnt(0)" ::: "memory");

        // ---- lane 0: ordered shoelace sum + iou + bit write ----
        if(l == 0){
            float acc = 0.f;
            #pragma unroll
            for(int kk=0;kk<24;++kk) acc += s_tm[wv][kk];
            float area = 0.5f*fabsf(acc);
            float inter_bev = (cntf >= 3.f) ? area : 0.f;
            float inter = inter_bev * oh;
            float iou = inter / fmaxf(voli+volj-inter, 1e-6f);
            if(iou > 0.1f){
                unsigned* adj32 = (unsigned*)adj;
                atomicOr(&adj32[i*(ADJW*2) + (jj>>5)], 1u << (jj&31));
            }
        }
    }
}

// single block: clustering (wave 0, pipelined seed-scan) + CSR fusion + outputs
__global__ __launch_bounds__(512) void cluster_fuse_kernel(
        const float* __restrict__ boxes,
        const float* __restrict__ scores,
        const ull* __restrict__ adj,
        const int* __restrict__ fhp,
        const int* __restrict__ fwp,
        float* __restrict__ out){
    const float PI_F      = 3.14159265358979323846f;
    const float HALF_PI_F = 1.57079632679489662f;
    const float TWO_PI_F  = 6.2831853071795864769f;
    int t = threadIdx.x;
    int lane = t & 63, w = t >> 6;

    __shared__ ull   s_adj[N*ADJW];   // 32 KB
    __shared__ float s_sc[N], s_dir[N];
    __shared__ int   s_ci[N];
    __shared__ int   s_cnt[N], s_off[N], s_pos[N], s_mem[N];
    __shared__ float s_dref[N], s_ssum[N], s_smax[N];
    __shared__ float s_val[8][N];
    __shared__ unsigned char s_keep[N];
    __shared__ int   s_wsum[8];

    float b0=boxes[t*7+0], b1=boxes[t*7+1], b2=boxes[t*7+2], b3=boxes[t*7+3],
          b4=boxes[t*7+4], b5=boxes[t*7+5], b6=boxes[t*7+6];
    float dir = limit_period_f(b6);
    float sc  = scores[t];
    s_sc[t] = sc;
    s_dir[t] = dir;
    s_cnt[t] = 0;
    #pragma unroll
    for(int k=0;k<ADJW;++k) s_adj[k*N + t] = adj[k*N + t];
    __syncthreads();

    // ---- clustering: wave 0, ascending seed scan with 8-deep byte prefetch ----
    if(t < 64){
        int mc[8] = {0,0,0,0,0,0,0,0};
        unsigned myset = 0u;
        int cid = 1;
        const unsigned char* ab = (const unsigned char*)s_adj;
        unsigned buf[8];
        #pragma unroll
        for(int k=0;k<8;++k) buf[k] = (unsigned)ab[k*64 + t];
        for(int c=0;c<64;++c){
            unsigned cur[8];
            #pragma unroll
            for(int k=0;k<8;++k) cur[k] = buf[k];
            if(c < 63){
                #pragma unroll
                for(int k=0;k<8;++k) buf[k] = (unsigned)ab[(c*8 + 8 + k)*64 + t];
            }
            bool owner = (t == c);
            #pragma unroll
            for(int k=0;k<8;++k){
                bool mine = owner && (((myset >> k) & 1u) == 0u);
                if(__ballot(mine)){
                    unsigned byte = cur[k];
                    #pragma unroll
                    for(int qq=0;qq<8;++qq){ if((byte>>qq)&1u) mc[qq] = cid; }
                    myset |= byte;
                    cid++;
                }
            }
        }
        #pragma unroll
        for(int k=0;k<8;++k) s_ci[t*8+k] = mc[k];
    }
    __syncthreads();

    // ---- per-segment counts via LDS atomics ----
    int myci = s_ci[t];
    atomicAdd(&s_cnt[myci-1], 1);
    __syncthreads();
    int icnt = s_cnt[t];            // thread t owns segment t+1

    // ---- exclusive prefix sum: shfl wave-scan + cross-wave fixup ----
    int v = icnt;
    #pragma unroll
    for(int d=1; d<64; d<<=1){
        int u = __shfl_up(v, d);
        if(lane >= d) v += u;
    }
    if(lane == 63) s_wsum[w] = v;
    __syncthreads();
    int woff = 0;
    #pragma unroll
    for(int k=0;k<8;++k){ if(k < w) woff += s_wsum[k]; }
    int excl = woff + v - icnt;
    s_off[t] = excl;
    s_pos[t] = excl;
    __syncthreads();

    // ---- scatter members (unordered), then owner sorts ascending ----
    int r = atomicAdd(&s_pos[myci-1], 1);
    s_mem[r] = t;
    __syncthreads();
    int base = s_off[t];
    for(int a=1;a<icnt;++a){
        int key = s_mem[base+a];
        int b = a-1;
        while(b >= 0 && s_mem[base+b] > key){ s_mem[base+b+1] = s_mem[base+b]; --b; }
        s_mem[base+b+1] = key;
    }

    // ---- owner reductions in exact ascending order ----
    float smax = -1e30f, ssum = 0.f;
    for(int k=0;k<icnt;++k){
        int i = s_mem[base+k];
        smax = fmaxf(smax, s_sc[i]);
        ssum += s_sc[i];
    }
    float dref = -1e9f;
    for(int k=0;k<icnt;++k){
        int i = s_mem[base+k];
        float vv = (s_sc[i] == smax) ? s_dir[i] : -1e9f;
        dref = fmaxf(dref, vv);
    }
    float slt = 0.f, sle = 0.f;
    for(int k=0;k<icnt;++k){
        int i = s_mem[base+k];
        float diff = fabsf(s_dir[i] - dref);
        diff = (diff > PI_F) ? (TWO_PI_F - diff) : diff;
        if(diff > HALF_PI_F) slt += s_sc[i]; else sle += s_sc[i];
    }
    s_smax[t] = smax;
    s_ssum[t] = ssum;
    s_dref[t] = dref;
    s_keep[t] = (slt <= sle) ? 1 : 0;
    __syncthreads();

    // ---- per-box: flip, dir2, sn, weighted values (trig once per box) ----
    {
        int ow = myci - 1;
        float drefb = s_dref[ow];
        float diff = fabsf(dir - drefb);
        diff = (diff > PI_F) ? (TWO_PI_F - diff) : diff;
        bool gt = diff > HALF_PI_F;
        bool keep = s_keep[ow] != 0;
        bool flip = keep ? gt : !gt;
        float d2 = limit_period_f(dir + (flip ? PI_F : 0.f));
        float sn = sc / s_ssum[ow];
        s_val[0][t] = sinf(d2)*sn;
        s_val[1][t] = cosf(d2)*sn;
        s_val[2][t] = b0*sn;
        s_val[3][t] = b1*sn;
        s_val[4][t] = b2*sn;
        s_val[5][t] = b3*sn;
        s_val[6][t] = b4*sn;
        s_val[7][t] = b5*sn;
    }
    __syncthreads();

    // ---- owner weighted sums (ascending member order) ----
    float ssin=0.f, scos=0.f;
    float cd[6] = {0.f,0.f,0.f,0.f,0.f,0.f};
    for(int k=0;k<icnt;++k){
        int i = s_mem[base+k];
        ssin  += s_val[0][i];
        scos  += s_val[1][i];
        cd[0] += s_val[2][i];
        cd[1] += s_val[3][i];
        cd[2] += s_val[4][i];
        cd[3] += s_val[5][i];
        cd[4] += s_val[6][i];
        cd[5] += s_val[7][i];
    }
    float theta = atan2f(ssin, scos);

    // ---- epilogue ----
    bool valid = icnt > 0;
    float bf[7];
    #pragma unroll
    for(int d=0;d<6;++d) bf[d] = valid ? cd[d] : 0.f;
    bf[6] = valid ? theta : 0.f;
    {
        float cth=cosf(bf[6]), sth=sinf(bf[6]);
        const float tx[4]={0.5f,0.5f,-0.5f,-0.5f};
        const float ty[4]={0.5f,-0.5f,-0.5f,0.5f};
        bool inb = true;
        #pragma unroll
        for(int k=0;k<4;++k){
            float pxl = tx[k]*bf[5], pyl = ty[k]*bf[4];
            float gx = pxl*cth - pyl*sth + bf[0];
            float gy = pxl*sth + pyl*cth + bf[1];
            inb = inb && (gx > -140.8f) && (gx < 140.8f) && (gy > -40.0f) && (gy < 40.0f);
        }
        valid = valid && inb;
    }
    if(!valid){
        #pragma unroll
        for(int d=0;d<7;++d) bf[d]=0.f;
    }
    float sf = valid ? s_smax[t] : 0.f;
    int fh = *fhp, fw = *fwp;
    float ghf = (float)((40.0 - (-40.0)) / (double)fh);
    float gwf = (float)((140.8 - (-140.8)) / (double)fw);
    float gcx = (bf[0] + 140.8f) / gwf;
    float gcy = (bf[1] + 40.0f) / ghf;
    float gox = bf[5]*0.5f / gwf;
    float goy = bf[4]*0.5f / ghf + 1.0f;
    float xmin = fmaxf(gcx - gox, 0.f);
    float xmax = fminf(gcx + gox, (float)fw - 1.0f);
    float ymin = fmaxf(gcy - goy, 0.f);
    float ymax = fminf(gcy + goy, (float)fh - 1.0f);
    int r0 = (int)xmin, r1 = (int)xmax, r2 = (int)ymin, r3 = (int)ymax;
    if(!valid){ r0=0; r1=0; r2=0; r3=0; }
    #pragma unroll
    for(int d=0;d<7;++d) out[t*7+d] = bf[d];
    out[N*7 + t] = sf;
    out[N*8 + t] = valid ? 1.f : 0.f;
    out[N*9 + t*4 + 0] = (float)r0;
    out[N*9 + t*4 + 1] = (float)r1;
    out[N*9 + t*4 + 2] = (float)r2;
    out[N*9 + t*4 + 3] = (float)r3;
}

extern "C" void kernel_launch(void* const* d_in, const int* in_sizes, int n_in,
                              void* d_out, int out_size, void* d_ws, size_t ws_size,
                              hipStream_t stream) {
    const float* boxes  = (const float*)d_in[0];
    const float* scores = (const float*)d_in[1];
    const int*   fhp    = (const int*)d_in[2];
    const int*   fwp    = (const int*)d_in[3];
    float* out = (float*)d_out;
    char* ws = (char*)d_ws;
    ull* adj    = (ull*)(ws + ADJ_OFF);       // 32768 B
    int* rowcnt = (int*)(ws + ROWCNT_OFF);    // 2048 B
    int* pairs  = (int*)(ws + PAIRS_OFF);     // 512*64*4 = 131072 B

    pair_kernel<<<N, 512, 0, stream>>>(boxes, adj, rowcnt, pairs);
    geom_kernel<<<N, 512, 0, stream>>>(boxes, pairs, rowcnt, adj);
    cluster_fuse_kernel<<<1, 512, 0, stream>>>(boxes, scores, adj, fhp, fwp, out);
}

// Round 10
// 48.916 us; speedup vs baseline: 1.7161x; 1.7161x over previous
//
#include <hip/hip_runtime.h>

#define N 512
#define ADJW (N/64)
#define MAXC 64
typedef unsigned long long ull;

__device__ __forceinline__ float limit_period_f(float v){
    const float TWO_PI_F = 6.2831853071795864769f;
    return v - floorf(v/TWO_PI_F + 0.5f)*TWO_PI_F;
}

// One block per row i. Phase 1: all 512 threads cheap-reject j=t, ballot-
// compact candidates (ascending j) into LDS; also stage all 512 boxes in LDS.
// Phase 2: 16 half-waves, each runs the lane-parallel polygon clip on ONE pair
// (slots on lanes 0..23 of the half); leaders (lane 0/32) do the ordered sums.
// Sequential chain depth per wave halves vs 1-pair-per-wave; rank uses LDS
// broadcast reads (not 24 serial shfls); chain reads boxes from LDS.
__global__ __launch_bounds__(512) void adj_kernel(const float* __restrict__ boxes,
                                                  ull* __restrict__ adj){
    int i = blockIdx.x;
    int t = threadIdx.x;
    int l = t & 63, wv = t >> 6;
    int h  = l >> 5;            // half id within wave (0/1)
    int sl = l & 31;            // slot lane within half (0..31; 0..23 active)
    int hb = wv*2 + h;          // half-chain index 0..15

    __shared__ int      s_wcnt[8];
    __shared__ int      s_list[MAXC];
    __shared__ unsigned s_row[ADJW*2];
    __shared__ float    s_boxes[N][7];
    __shared__ float    s_px[16][24], s_py[16][24], s_ang[16][24];
    __shared__ float    s_rx[16][24], s_ry[16][24], s_tm[16][24];

    if(t < ADJW*2) s_row[t] = 0u;

    // ---- phase 1: cheap conservative reject for j = t; stage boxes in LDS ----
    float bi0=boxes[i*7+0], bi1=boxes[i*7+1], bi2=boxes[i*7+2], bi3=boxes[i*7+3],
          bi4=boxes[i*7+4], bi5=boxes[i*7+5], bi6=boxes[i*7+6];
    int j = t;
    float bj0=boxes[j*7+0], bj1=boxes[j*7+1], bj2=boxes[j*7+2], bj3=boxes[j*7+3],
          bj4=boxes[j*7+4], bj5=boxes[j*7+5], bj6=boxes[j*7+6];
    s_boxes[t][0]=bj0; s_boxes[t][1]=bj1; s_boxes[t][2]=bj2; s_boxes[t][3]=bj3;
    s_boxes[t][4]=bj4; s_boxes[t][5]=bj5; s_boxes[t][6]=bj6;

    float topi = bi2 + bi3*0.5f, boti = bi2 - bi3*0.5f;
    float topj = bj2 + bj3*0.5f, botj = bj2 - bj3*0.5f;
    float ohc = fminf(topi, topj) - fmaxf(boti, botj);
    float dx = bi0 - bj0, dy = bi1 - bj1;
    float ra = 0.5f*sqrtf(bi5*bi5 + bi4*bi4);
    float rb = 0.5f*sqrtf(bj5*bj5 + bj4*bj4);
    float rr = ra + rb + 0.01f;
    bool cand = (dx*dx + dy*dy <= rr*rr) && (ohc > 0.0f);

    ull m = __ballot(cand);
    if(l == 0) s_wcnt[wv] = __popcll(m);
    int prefix = __popcll(m & ((1ull<<l) - 1ull));
    __syncthreads();
    int base = 0, C = 0;
    #pragma unroll
    for(int k=0;k<8;++k){ int c = s_wcnt[k]; if(k < wv) base += c; C += c; }
    if(cand){
        int pos = base + prefix;
        if(pos < MAXC) s_list[pos] = j;
    }
    if(C > MAXC) C = MAXC;
    __syncthreads();

    // ---- phase 2: dual-half lane-parallel geometry ----
    float voli = bi3*bi4*bi5;
    const float tx[4] = {0.5f, 0.5f, -0.5f, -0.5f};
    const float ty[4] = {0.5f, -0.5f, -0.5f, 0.5f};
    float yawi = limit_period_f(bi6);
    float cA = cosf(yawi), sA = sinf(yawi);
    float axv[4], ayv[4];
    #pragma unroll
    for(int k=0;k<4;++k){
        float px = tx[k]*bi5, py = ty[k]*bi4;
        axv[k] = px*cA - py*sA + bi0;
        ayv[k] = px*sA + py*cA + bi1;
    }

    for(int k = hb; k < C; k += 16){
        int jj = s_list[k];
        float cj0=s_boxes[jj][0], cj1=s_boxes[jj][1], cj2=s_boxes[jj][2],
              cj3=s_boxes[jj][3], cj4=s_boxes[jj][4], cj5=s_boxes[jj][5],
              cj6=s_boxes[jj][6];
        float volj = cj3*cj4*cj5;
        float topj2 = cj2 + cj3*0.5f, botj2 = cj2 - cj3*0.5f;
        float oh = fminf(topi, topj2) - fmaxf(boti, botj2);  // > 0 for candidates
        float yawj = limit_period_f(cj6);
        float cB = cosf(yawj), sB = sinf(yawj);
        float bxv[4], byv[4];
        #pragma unroll
        for(int kk=0;kk<4;++kk){
            float qx = tx[kk]*cj5, qy = ty[kk]*cj4;
            bxv[kk] = qx*cB - qy*sB + cj0;
            byv[kk] = qx*sB + qy*cB + cj1;
        }

        // ---- per-slot candidate on slot lane sl ----
        const float EPSQ = 1e-5f;
        bool valid = false;
        float px = 0.f, py = 0.f;
        if(sl < 16){
            int e1 = sl >> 2, e2 = sl & 3;
            float a1x=axv[e1], a1y=ayv[e1];
            float d1x=axv[(e1+1)&3]-a1x, d1y=ayv[(e1+1)&3]-a1y;
            float b1x=bxv[e2], b1y=byv[e2];
            float d2x=bxv[(e2+1)&3]-b1x, d2y=byv[(e2+1)&3]-b1y;
            float den = d1x*d2y - d1y*d2x;
            bool okd = fabsf(den) > 1e-8f;
            float dens = okd ? den : 1e-8f;
            float wx = b1x-a1x, wy = b1y-a1y;
            float tt = (wx*d2y - wy*d2x)/dens;
            float uu = (wx*d1y - wy*d1x)/dens;
            valid = okd && (tt>=0.f) && (tt<=1.f) && (uu>=0.f) && (uu<=1.f);
            px = a1x + tt*d1x;
            py = a1y + tt*d1y;
        } else if(sl < 20){
            int kk = sl - 16;
            px = axv[kk]; py = ayv[kk];
            bool le=true, ge=true;
            #pragma unroll
            for(int e=0;e<4;++e){
                float qx=bxv[e], qy=byv[e];
                float ux=bxv[(e+1)&3]-qx, uy=byv[(e+1)&3]-qy;
                float cc = ux*(py-qy) - uy*(px-qx);
                le = le && (cc <= EPSQ);
                ge = ge && (cc >= -EPSQ);
            }
            valid = le || ge;
        } else if(sl < 24){
            int kk = sl - 20;
            px = bxv[kk]; py = byv[kk];
            bool le=true, ge=true;
            #pragma unroll
            for(int e=0;e<4;++e){
                float qx=axv[e], qy=ayv[e];
                float ux=axv[(e+1)&3]-qx, uy=ayv[(e+1)&3]-qy;
                float cc = ux*(py-qy) - uy*(px-qx);
                le = le && (cc <= EPSQ);
                ge = ge && (cc >= -EPSQ);
            }
            valid = le || ge;
        }

        ull bm = __ballot(valid);
        unsigned mh = (unsigned)(bm >> (h*32)) & 0xFFFFFFu;
        int c = __popc(mh);
        float cntf = (float)c;

        // ---- centroid: leader sums 24 slot values in slot order ----
        if(sl < 24){
            s_px[hb][sl] = valid ? px : 0.f;
            s_py[hb][sl] = valid ? py : 0.f;
        }
        asm volatile("s_waitcnt lgkmcnt(0)" ::: "memory");
        float sx = 0.f, sy = 0.f;
        if(sl == 0){
            #pragma unroll
            for(int kk=0;kk<24;++kk){ sx += s_px[hb][kk]; sy += s_py[hb][kk]; }
        }
        sx = __shfl(sx, l & 32);
        sy = __shfl(sy, l & 32);
        float denomc = fmaxf(cntf, 1.f);
        float cenx = sx/denomc, ceny = sy/denomc;

        // ---- rel + parallel atan2 ----
        float relx = valid ? (px - cenx) : 0.f;
        float rely = valid ? (py - ceny) : 0.f;
        float ang  = valid ? atan2f(rely, relx) : 1e9f;

        // ---- stable rank via LDS broadcast reads (no serial shfl chain) ----
        if(sl < 24) s_ang[hb][sl] = ang;
        asm volatile("s_waitcnt lgkmcnt(0)" ::: "memory");
        int r = 0;
        if(sl < 24){
            #pragma unroll
            for(int qq=0; qq<24; ++qq){
                float aq = s_ang[hb][qq];
                if(aq < ang) r++;
                else if(aq == ang && qq < sl) r++;
            }
        }

        // ---- scatter rel by rank; cross-term per sorted position ----
        if(sl < 24){
            s_rx[hb][r] = relx;
            s_ry[hb][r] = rely;
        }
        asm volatile("s_waitcnt lgkmcnt(0)" ::: "memory");
        if(sl < 24){
            int nxt = (r+1 < c) ? (r+1) : 0;
            float nx = s_rx[hb][nxt], ny = s_ry[hb][nxt];
            float tm = (r < c) ? (relx*ny - rely*nx) : 0.f;
            s_tm[hb][r] = tm;
        }
        asm volatile("s_waitcnt lgkmcnt(0)" ::: "memory");

        // ---- leader: ordered shoelace sum + iou + bit set ----
        if(sl == 0){
            float acc = 0.f;
            #pragma unroll
            for(int kk=0;kk<24;++kk) acc += s_tm[hb][kk];
            float area = 0.5f*fabsf(acc);
            float inter_bev = (cntf >= 3.f) ? area : 0.f;
            float inter = inter_bev * oh;
            float iou = inter / fmaxf(voli+volj-inter, 1e-6f);
            if(iou > 0.1f) atomicOr(&s_row[jj>>5], 1u << (jj&31));
        }
    }
    __syncthreads();
    if(t < ADJW) adj[i*ADJW + t] = ((ull*)s_row)[t];
}

// single block: clustering (wave 0, pipelined seed-scan) + CSR fusion + outputs
__global__ __launch_bounds__(512) void cluster_fuse_kernel(
        const float* __restrict__ boxes,
        const float* __restrict__ scores,
        const ull* __restrict__ adj,
        const int* __restrict__ fhp,
        const int* __restrict__ fwp,
        float* __restrict__ out){
    const float PI_F      = 3.14159265358979323846f;
    const float HALF_PI_F = 1.57079632679489662f;
    const float TWO_PI_F  = 6.2831853071795864769f;
    int t = threadIdx.x;
    int lane = t & 63, w = t >> 6;

    __shared__ ull   s_adj[N*ADJW];   // 32 KB
    __shared__ float s_sc[N], s_dir[N];
    __shared__ int   s_ci[N];
    __shared__ int   s_cnt[N], s_off[N], s_pos[N], s_mem[N];
    __shared__ float s_dref[N], s_ssum[N], s_smax[N];
    __shared__ float s_val[8][N];
    __shared__ unsigned char s_keep[N];
    __shared__ int   s_wsum[8];

    float b0=boxes[t*7+0], b1=boxes[t*7+1], b2=boxes[t*7+2], b3=boxes[t*7+3],
          b4=boxes[t*7+4], b5=boxes[t*7+5], b6=boxes[t*7+6];
    float dir = limit_period_f(b6);
    float sc  = scores[t];
    s_sc[t] = sc;
    s_dir[t] = dir;
    s_cnt[t] = 0;
    #pragma unroll
    for(int k=0;k<ADJW;++k) s_adj[k*N + t] = adj[k*N + t];
    __syncthreads();

    // ---- clustering: wave 0, ascending seed scan with 8-deep byte prefetch ----
    if(t < 64){
        int mc[8] = {0,0,0,0,0,0,0,0};
        unsigned myset = 0u;
        int cid = 1;
        const unsigned char* ab = (const unsigned char*)s_adj;
        unsigned buf[8];
        #pragma unroll
        for(int k=0;k<8;++k) buf[k] = (unsigned)ab[k*64 + t];
        for(int c=0;c<64;++c){
            unsigned cur[8];
            #pragma unroll
            for(int k=0;k<8;++k) cur[k] = buf[k];
            if(c < 63){
                #pragma unroll
                for(int k=0;k<8;++k) buf[k] = (unsigned)ab[(c*8 + 8 + k)*64 + t];
            }
            bool owner = (t == c);
            #pragma unroll
            for(int k=0;k<8;++k){
                bool mine = owner && (((myset >> k) & 1u) == 0u);
                if(__ballot(mine)){
                    unsigned byte = cur[k];
                    #pragma unroll
                    for(int qq=0;qq<8;++qq){ if((byte>>qq)&1u) mc[qq] = cid; }
                    myset |= byte;
                    cid++;
                }
            }
        }
        #pragma unroll
        for(int k=0;k<8;++k) s_ci[t*8+k] = mc[k];
    }
    __syncthreads();

    // ---- per-segment counts via LDS atomics ----
    int myci = s_ci[t];
    atomicAdd(&s_cnt[myci-1], 1);
    __syncthreads();
    int icnt = s_cnt[t];            // thread t owns segment t+1

    // ---- exclusive prefix sum: shfl wave-scan + cross-wave fixup ----
    int v = icnt;
    #pragma unroll
    for(int d=1; d<64; d<<=1){
        int u = __shfl_up(v, d);
        if(lane >= d) v += u;
    }
    if(lane == 63) s_wsum[w] = v;
    __syncthreads();
    int woff = 0;
    #pragma unroll
    for(int k=0;k<8;++k){ if(k < w) woff += s_wsum[k]; }
    int excl = woff + v - icnt;
    s_off[t] = excl;
    s_pos[t] = excl;
    __syncthreads();

    // ---- scatter members (unordered), then owner sorts ascending ----
    int r = atomicAdd(&s_pos[myci-1], 1);
    s_mem[r] = t;
    __syncthreads();
    int base = s_off[t];
    for(int a=1;a<icnt;++a){
        int key = s_mem[base+a];
        int b = a-1;
        while(b >= 0 && s_mem[base+b] > key){ s_mem[base+b+1] = s_mem[base+b]; --b; }
        s_mem[base+b+1] = key;
    }

    // ---- owner reductions in exact ascending order ----
    float smax = -1e30f, ssum = 0.f;
    for(int k=0;k<icnt;++k){
        int i = s_mem[base+k];
        smax = fmaxf(smax, s_sc[i]);
        ssum += s_sc[i];
    }
    float dref = -1e9f;
    for(int k=0;k<icnt;++k){
        int i = s_mem[base+k];
        float vv = (s_sc[i] == smax) ? s_dir[i] : -1e9f;
        dref = fmaxf(dref, vv);
    }
    float slt = 0.f, sle = 0.f;
    for(int k=0;k<icnt;++k){
        int i = s_mem[base+k];
        float diff = fabsf(s_dir[i] - dref);
        diff = (diff > PI_F) ? (TWO_PI_F - diff) : diff;
        if(diff > HALF_PI_F) slt += s_sc[i]; else sle += s_sc[i];
    }
    s_smax[t] = smax;
    s_ssum[t] = ssum;
    s_dref[t] = dref;
    s_keep[t] = (slt <= sle) ? 1 : 0;
    __syncthreads();

    // ---- per-box: flip, dir2, sn, weighted values (trig once per box) ----
    {
        int ow = myci - 1;
        float drefb = s_dref[ow];
        float diff = fabsf(dir - drefb);
        diff = (diff > PI_F) ? (TWO_PI_F - diff) : diff;
        bool gt = diff > HALF_PI_F;
        bool keep = s_keep[ow] != 0;
        bool flip = keep ? gt : !gt;
        float d2 = limit_period_f(dir + (flip ? PI_F : 0.f));
        float sn = sc / s_ssum[ow];
        s_val[0][t] = sinf(d2)*sn;
        s_val[1][t] = cosf(d2)*sn;
        s_val[2][t] = b0*sn;
        s_val[3][t] = b1*sn;
        s_val[4][t] = b2*sn;
        s_val[5][t] = b3*sn;
        s_val[6][t] = b4*sn;
        s_val[7][t] = b5*sn;
    }
    __syncthreads();

    // ---- owner weighted sums (ascending member order) ----
    float ssin=0.f, scos=0.f;
    float cd[6] = {0.f,0.f,0.f,0.f,0.f,0.f};
    for(int k=0;k<icnt;++k){
        int i = s_mem[base+k];
        ssin  += s_val[0][i];
        scos  += s_val[1][i];
        cd[0] += s_val[2][i];
        cd[1] += s_val[3][i];
        cd[2] += s_val[4][i];
        cd[3] += s_val[5][i];
        cd[4] += s_val[6][i];
        cd[5] += s_val[7][i];
    }
    float theta = atan2f(ssin, scos);

    // ---- epilogue ----
    bool valid = icnt > 0;
    float bf[7];
    #pragma unroll
    for(int d=0;d<6;++d) bf[d] = valid ? cd[d] : 0.f;
    bf[6] = valid ? theta : 0.f;
    {
        float cth=cosf(bf[6]), sth=sinf(bf[6]);
        const float tx[4]={0.5f,0.5f,-0.5f,-0.5f};
        const float ty[4]={0.5f,-0.5f,-0.5f,0.5f};
        bool inb = true;
        #pragma unroll
        for(int k=0;k<4;++k){
            float pxl = tx[k]*bf[5], pyl = ty[k]*bf[4];
            float gx = pxl*cth - pyl*sth + bf[0];
            float gy = pxl*sth + pyl*cth + bf[1];
            inb = inb && (gx > -140.8f) && (gx < 140.8f) && (gy > -40.0f) && (gy < 40.0f);
        }
        valid = valid && inb;
    }
    if(!valid){
        #pragma unroll
        for(int d=0;d<7;++d) bf[d]=0.f;
    }
    float sf = valid ? s_smax[t] : 0.f;
    int fh = *fhp, fw = *fwp;
    float ghf = (float)((40.0 - (-40.0)) / (double)fh);
    float gwf = (float)((140.8 - (-140.8)) / (double)fw);
    float gcx = (bf[0] + 140.8f) / gwf;
    float gcy = (bf[1] + 40.0f) / ghf;
    float gox = bf[5]*0.5f / gwf;
    float goy = bf[4]*0.5f / ghf + 1.0f;
    float xmin = fmaxf(gcx - gox, 0.f);
    float xmax = fminf(gcx + gox, (float)fw - 1.0f);
    float ymin = fmaxf(gcy - goy, 0.f);
    float ymax = fminf(gcy + goy, (float)fh - 1.0f);
    int r0 = (int)xmin, r1 = (int)xmax, r2 = (int)ymin, r3 = (int)ymax;
    if(!valid){ r0=0; r1=0; r2=0; r3=0; }
    #pragma unroll
    for(int d=0;d<7;++d) out[t*7+d] = bf[d];
    out[N*7 + t] = sf;
    out[N*8 + t] = valid ? 1.f : 0.f;
    out[N*9 + t*4 + 0] = (float)r0;
    out[N*9 + t*4 + 1] = (float)r1;
    out[N*9 + t*4 + 2] = (float)r2;
    out[N*9 + t*4 + 3] = (float)r3;
}

extern "C" void kernel_launch(void* const* d_in, const int* in_sizes, int n_in,
                              void* d_out, int out_size, void* d_ws, size_t ws_size,
                              hipStream_t stream) {
    const float* boxes  = (const float*)d_in[0];
    const float* scores = (const float*)d_in[1];
    const int*   fhp    = (const int*)d_in[2];
    const int*   fwp    = (const int*)d_in[3];
    float* out = (float*)d_out;
    ull* adj = (ull*)d_ws;               // 512*8*8 = 32768 bytes

    adj_kernel<<<N, 512, 0, stream>>>(boxes, adj);
    cluster_fuse_kernel<<<1, 512, 0, stream>>>(boxes, scores, adj, fhp, fwp, out);
}